// Round 13
// baseline (353.664 us; speedup 1.0000x reference)
//
#include <hip/hip_runtime.h>

typedef __bf16 bf16_t;
typedef __bf16 bf16x8 __attribute__((ext_vector_type(8)));
typedef float f32x4 __attribute__((ext_vector_type(4)));

#define B_TOTAL 262144
#define OUTC 324
#define ROWS 128

// d_ws layout (bf16 element offsets)
#define OFF_WIN   0        // [64][32]
#define OFF_WG    2048     // [256][256] gate-major: n = g*64 + j; K = [x64|msgs128|h64]
#define OFF_WM1   67584    // [4][112][64]
#define OFF_WM2   96256    // [4][32][128]
#define OFF_WU1   112640   // [112][64]
#define OFF_WU2   119808   // [112][128]
#define OFF_WU3   134144   // [64][128]
#define OFF_WMV2  142336   // [32][112] fused (Wmu;Wvar)·Wu3
#define BF16_TOTAL 145920
// f32: bg[256] at byte BF16_TOTAL*2; bmv[32] after

__global__ void prep_kernel(const float* W_in, const float* msg_W1, const float* msg_W2,
                            const float* W_ih, const float* W_hh, const float* b_ih, const float* b_hh,
                            const float* W_u1, const float* W_u2, const float* W_u3, const float* b_u3f,
                            const float* W_mu, const float* W_var, const float* b_mu, const float* b_var,
                            bf16_t* wb, float* bg, float* bmv) {
  int tid = blockIdx.x * blockDim.x + threadIdx.x;
  int nth = gridDim.x * blockDim.x;
  for (int i = tid; i < 2048; i += nth) wb[OFF_WIN + i] = (bf16_t)W_in[i];
  for (int i = tid; i < 65536; i += nth) {
    int n = i >> 8, k = i & 255;
    int g = n >> 6, j = n & 63;
    float v = 0.f;
    if (j < 50) {
      int r = g * 50 + j;
      if (k < 192) v = W_ih[r * 192 + k];
      else if (k < 242) v = W_hh[r * 50 + (k - 192)];
    }
    wb[OFF_WG + i] = (bf16_t)v;
  }
  for (int i = tid; i < 256; i += nth) {
    int g = i >> 6, j = i & 63;
    bg[i] = (j < 50) ? (b_ih[g * 50 + j] + b_hh[g * 50 + j]) : 0.f;
  }
  for (int i = tid; i < 4 * 112 * 64; i += nth) {
    int p = i / (112 * 64); int rem = i % (112 * 64); int n = rem >> 6, k = rem & 63;
    wb[OFF_WM1 + i] = (bf16_t)((n < 100) ? msg_W1[(p * 100 + n) * 64 + k] : 0.f);
  }
  for (int i = tid; i < 4 * 32 * 128; i += nth) {
    int p = i / (32 * 128); int rem = i % (32 * 128); int n = rem >> 7, k = rem & 127;
    wb[OFF_WM2 + i] = (bf16_t)((k < 100) ? msg_W2[(p * 32 + n) * 100 + k] : 0.f);
  }
  for (int i = tid; i < 112 * 64; i += nth) {
    int n = i >> 6, k = i & 63;
    wb[OFF_WU1 + i] = (bf16_t)((n < 100 && k < 50) ? W_u1[n * 50 + k] : 0.f);
  }
  for (int i = tid; i < 112 * 128; i += nth) {
    int n = i >> 7, k = i & 127;
    wb[OFF_WU2 + i] = (bf16_t)((n < 100 && k < 100) ? W_u2[n * 100 + k] : 0.f);
  }
  for (int i = tid; i < 64 * 128; i += nth) {
    int n = i >> 7, k = i & 127;
    wb[OFF_WU3 + i] = (bf16_t)((k < 100) ? W_u3[n * 100 + k] : 0.f);
  }
  for (int i = tid; i < 32 * 112; i += nth) {
    int o = i / 112, h = i % 112;
    float v = 0.f;
    if (h < 100) {
      const float* wrow = (o < 16) ? (W_mu + o * 64) : (W_var + (o - 16) * 64);
      for (int s = 0; s < 64; s++) v += wrow[s] * W_u3[s * 100 + h];
    }
    wb[OFF_WMV2 + i] = (bf16_t)v;
  }
  for (int i = tid; i < 32; i += nth) {
    int o = i;
    const float* wrow = (o < 16) ? (W_mu + o * 64) : (W_var + (o - 16) * 64);
    float v = (o < 16) ? b_mu[o] : b_var[o - 16];
    for (int s = 0; s < 64; s++) v += wrow[s] * b_u3f[s];
    bmv[o] = v;
  }
}

#define MFMA(a, b, c) __builtin_amdgcn_mfma_f32_16x16x32_bf16((a), (b), (c), 0, 0, 0)

__device__ __forceinline__ float frcp(float x) { return __builtin_amdgcn_rcpf(x); }
__device__ __forceinline__ float fsigmoid(float x) { return frcp(1.f + __expf(-x)); }
__device__ __forceinline__ float ftanh_f(float x) { return 1.f - 2.f * frcp(1.f + __expf(2.f * x)); }
__device__ __forceinline__ float fsoftplus(float x) { return (x > 15.f) ? x : __logf(1.f + __expf(x)); }

__device__ __forceinline__ bf16x8 cvt8(const float* __restrict__ p) {
  float4 v0 = *(const float4*)p;
  float4 v1 = *(const float4*)(p + 4);
  bf16x8 r;
  r[0] = (bf16_t)v0.x; r[1] = (bf16_t)v0.y; r[2] = (bf16_t)v0.z; r[3] = (bf16_t)v0.w;
  r[4] = (bf16_t)v1.x; r[5] = (bf16_t)v1.y; r[6] = (bf16_t)v1.z; r[7] = (bf16_t)v1.w;
  return r;
}

// S2: m1(p) = relu(x @ W1p^T + b1p) -> dst[:,0:112]. Wave w owns n-tile nt=w (<7), m=8.
// Weights read ONCE per 128-row block.
__device__ __forceinline__ void stage2(int p, const bf16x8 ax[8][2], bf16_t* dst,
                                       const bf16_t* __restrict__ wb,
                                       const float* __restrict__ msg_b1,
                                       int w, int lr, int kq) {
  for (int nt = w; nt < 7; nt += 8) {
    int nb = nt * 16;
    float bv = (nb + lr < 100) ? msg_b1[p * 100 + nb + lr] : 0.f;
    const bf16_t* Bp = wb + OFF_WM1 + p * 112 * 64 + (nb + lr) * 64 + kq * 8;
    bf16x8 b0 = *(const bf16x8*)Bp;
    bf16x8 b1 = *(const bf16x8*)(Bp + 32);
#pragma unroll
    for (int m = 0; m < 8; m++) {
      f32x4 acc = {bv, bv, bv, bv};
      acc = MFMA(ax[m][0], b0, acc);
      acc = MFMA(ax[m][1], b1, acc);
#pragma unroll
      for (int rr = 0; rr < 4; rr++)
        dst[(m * 16 + kq * 4 + rr) * 120 + nb + lr] = (bf16_t)fmaxf(acc[rr], 0.f);
    }
  }
}

// S3: msgs(p). Wave w: n-tile = w&1, m-tiles {w>>1, (w>>1)+4}.
__device__ __forceinline__ void stage3(int p, const bf16_t* src,
                                       const bf16_t* __restrict__ wb,
                                       const float* __restrict__ msg_b2,
                                       float* __restrict__ out,
                                       int row0, int w, int lr, int kq) {
  int nb = (w & 1) * 16;
  float bv = msg_b2[p * 32 + nb + lr];
  const bf16_t* Bp = wb + OFF_WM2 + p * 32 * 128 + (nb + lr) * 128 + kq * 8;
  bf16x8 b[4];
#pragma unroll
  for (int c = 0; c < 4; c++) b[c] = *(const bf16x8*)(Bp + c * 32);
#pragma unroll
  for (int mi = 0; mi < 2; mi++) {
    int m = (w >> 1) + mi * 4;
    f32x4 acc = {bv, bv, bv, bv};
#pragma unroll
    for (int c = 0; c < 4; c++) {
      bf16x8 a;
      if (c < 3) {
        a = *(const bf16x8*)(src + (m * 16 + lr) * 120 + c * 32 + kq * 8);
      } else {
        bf16x8 z = {};
        a = (kq < 2) ? *(const bf16x8*)(src + (m * 16 + lr) * 120 + 96 + kq * 8) : z;
      }
      acc = MFMA(a, b[c], acc);
    }
#pragma unroll
    for (int rr = 0; rr < 4; rr++) {
      size_t row = row0 + m * 16 + kq * 4 + rr;
      out[row * OUTC + 32 + p * 32 + nb + lr] = acc[rr];
    }
  }
}

// LDS: xh[128][72] (x -> live through S4; hn overwrites j-cols after), tA[128][120], tB[128][120]
// = 79872 B -> 2 blocks/CU x 8 waves = 16 waves/CU (same as R12, half the per-row overhead).
__global__ __launch_bounds__(512, 2) void fused_kernel(
    const float* __restrict__ obs, const float* __restrict__ msg_in,
    const float* __restrict__ h_lstm, const float* __restrict__ c_lstm,
    const float* __restrict__ b_in, const float* __restrict__ msg_b1,
    const float* __restrict__ msg_b2, const float* __restrict__ b_u1,
    const float* __restrict__ b_u2, const float* __restrict__ b_u3,
    const float* __restrict__ maxlv, const float* __restrict__ minlv,
    const bf16_t* __restrict__ wb, const float* __restrict__ bg,
    const float* __restrict__ bmv, float* __restrict__ out) {
  __shared__ __align__(16) bf16_t xh[ROWS * 72];
  __shared__ __align__(16) bf16_t tA[ROWS * 120];
  __shared__ __align__(16) bf16_t tB[ROWS * 120];

  const int tid = threadIdx.x;
  const int row0 = blockIdx.x * ROWS;
  const int lane = tid & 63;
  const int w = tid >> 6;        // 0..7
  const int lr = lane & 15;
  const int kq = lane >> 4;

  // ---- S1: x = relu(obs @ Win^T + b_in) -> xh. wave: n-tile w&3, row-half w>>2 ----
  {
    int nb = (w & 3) * 16;
    int rh = w >> 2;
    float bv = b_in[nb + lr];
    bf16x8 b0 = *(const bf16x8*)(wb + OFF_WIN + (nb + lr) * 32 + kq * 8);
#pragma unroll
    for (int m = 0; m < 4; m++) {
      int lrow = rh * 64 + m * 16;
      bf16x8 a0 = cvt8(obs + (size_t)(row0 + lrow + lr) * 32 + kq * 8);
      f32x4 acc = {bv, bv, bv, bv};
      acc = MFMA(a0, b0, acc);
#pragma unroll
      for (int rr = 0; rr < 4; rr++)
        xh[(lrow + kq * 4 + rr) * 72 + nb + lr] = (bf16_t)fmaxf(acc[rr], 0.f);
    }
  }
  __syncthreads();  // B1

  // hoist x A-fragments for S2 (all 8 m-tiles; dead after stage2(3))
  bf16x8 ax[8][2];
#pragma unroll
  for (int m = 0; m < 8; m++)
#pragma unroll
    for (int k = 0; k < 2; k++)
      ax[m][k] = *(const bf16x8*)(xh + (m * 16 + lr) * 72 + k * 32 + kq * 8);

  stage2(0, ax, tA, wb, msg_b1, w, lr, kq);
  __syncthreads();  // B2

  stage3(0, tA, wb, msg_b2, out, row0, w, lr, kq);
  stage2(1, ax, tB, wb, msg_b1, w, lr, kq);
  __syncthreads();  // B3
  stage3(1, tB, wb, msg_b2, out, row0, w, lr, kq);
  stage2(2, ax, tA, wb, msg_b1, w, lr, kq);
  __syncthreads();  // B4
  stage3(2, tA, wb, msg_b2, out, row0, w, lr, kq);
  stage2(3, ax, tB, wb, msg_b1, w, lr, kq);
  __syncthreads();  // B5

  // ---- window: S3(3) || S4 gates. wave: j-slice w&3 (j=16(w&3)+lr), row-half w>>2 ----
  {
    const int j = (w & 3) * 16 + lr;
    const int rh = w >> 2;
    float c_pre[4][4];
#pragma unroll
    for (int ms = 0; ms < 4; ms++)
#pragma unroll
      for (int rr = 0; rr < 4; rr++) {
        size_t row = row0 + rh * 64 + ms * 16 + kq * 4 + rr;
        c_pre[ms][rr] = (j < 50) ? c_lstm[row * 50 + j] : 0.f;
      }

    stage3(3, tB, wb, msg_b2, out, row0, w, lr, kq);

    f32x4 acc[4][4];  // [gate][ms]
#pragma unroll
    for (int g = 0; g < 4; g++) {
      float bb = bg[g * 64 + j];
      f32x4 bi = {bb, bb, bb, bb};
#pragma unroll
      for (int ms = 0; ms < 4; ms++) acc[g][ms] = bi;
    }
#pragma unroll
    for (int c = 0; c < 8; c++) {
      bf16x8 a[4];
#pragma unroll
      for (int ms = 0; ms < 4; ms++) {
        int lrow = rh * 64 + ms * 16 + lr;
        if (c < 2) {
          a[ms] = *(const bf16x8*)(xh + lrow * 72 + c * 32 + kq * 8);
        } else if (c < 6) {
          a[ms] = cvt8(msg_in + ((size_t)(c - 2) * B_TOTAL + row0 + lrow) * 32 + kq * 8);
        } else if (c == 6) {
          a[ms] = cvt8(h_lstm + (size_t)(row0 + lrow) * 50 + kq * 8);
        } else {
          const float* hp = h_lstm + (size_t)(row0 + lrow) * 50;
          if (kq < 2) {
            a[ms] = cvt8(hp + 32 + kq * 8);
          } else if (kq == 2) {
            bf16x8 r = {};
            float2 v = *(const float2*)(hp + 48);
            r[0] = (bf16_t)v.x; r[1] = (bf16_t)v.y;
            a[ms] = r;
          } else {
            bf16x8 r = {};
            a[ms] = r;
          }
        }
      }
      bf16x8 bfr[4];
#pragma unroll
      for (int g = 0; g < 4; g++)
        bfr[g] = *(const bf16x8*)(wb + OFF_WG + (size_t)(g * 64 + j) * 256 + c * 32 + kq * 8);
#pragma unroll
      for (int g = 0; g < 4; g++)
#pragma unroll
        for (int ms = 0; ms < 4; ms++)
          acc[g][ms] = MFMA(a[ms], bfr[g], acc[g][ms]);
    }
    // LSTM epilogue; hn -> tA (tA's port-2 m1 is dead: S3(2) done before B5)
#pragma unroll
    for (int ms = 0; ms < 4; ms++) {
#pragma unroll
      for (int rr = 0; rr < 4; rr++) {
        int lrow = rh * 64 + ms * 16 + kq * 4 + rr;
        size_t row = row0 + lrow;
        float si = fsigmoid(acc[0][ms][rr]);
        float sf = fsigmoid(acc[1][ms][rr]);
        float gv = ftanh_f(acc[2][ms][rr]);
        float so = fsigmoid(acc[3][ms][rr]);
        float cn = sf * c_pre[ms][rr] + si * gv;
        float hv = so * ftanh_f(cn);
        if (j < 50) {
          out[row * OUTC + 274 + j] = cn;
          out[row * OUTC + 224 + j] = hv;
        }
        tA[lrow * 120 + j] = (bf16_t)((j < 50) ? hv : 0.f);
      }
    }
  }
  __syncthreads();  // B6

  // ---- S6: h2a = relu(hn @ Wu1^T + b_u1) -> tB. Wave w owns nt=w (<7), m=8 ----
  for (int nt = w; nt < 7; nt += 8) {
    int nb = nt * 16;
    float bv = (nb + lr < 100) ? b_u1[nb + lr] : 0.f;
    const bf16_t* Bp = wb + OFF_WU1 + (nb + lr) * 64 + kq * 8;
    bf16x8 b0 = *(const bf16x8*)Bp;
    bf16x8 b1 = *(const bf16x8*)(Bp + 32);
#pragma unroll
    for (int m = 0; m < 8; m++) {
      bf16x8 a0 = *(const bf16x8*)(tA + (m * 16 + lr) * 120 + kq * 8);
      bf16x8 a1 = *(const bf16x8*)(tA + (m * 16 + lr) * 120 + kq * 8 + 32);
      f32x4 acc = {bv, bv, bv, bv};
      acc = MFMA(a0, b0, acc);
      acc = MFMA(a1, b1, acc);
#pragma unroll
      for (int rr = 0; rr < 4; rr++)
        tB[(m * 16 + kq * 4 + rr) * 120 + nb + lr] = (bf16_t)fmaxf(acc[rr], 0.f);
    }
  }
  __syncthreads();  // B7

  // ---- S7: h2b = relu(h2a @ Wu2^T + b_u2) -> tA. Wave w owns nt=w (<7), m=8 ----
  for (int nt = w; nt < 7; nt += 8) {
    int nb = nt * 16;
    float bv = (nb + lr < 100) ? b_u2[nb + lr] : 0.f;
    const bf16_t* Bp = wb + OFF_WU2 + (nb + lr) * 128 + kq * 8;
    bf16x8 b[4];
#pragma unroll
    for (int c = 0; c < 4; c++) b[c] = *(const bf16x8*)(Bp + c * 32);
#pragma unroll
    for (int m = 0; m < 8; m++) {
      f32x4 acc = {bv, bv, bv, bv};
#pragma unroll
      for (int c = 0; c < 4; c++) {
        bf16x8 a;
        if (c < 3) {
          a = *(const bf16x8*)(tB + (m * 16 + lr) * 120 + c * 32 + kq * 8);
        } else {
          bf16x8 z = {};
          a = (kq < 2) ? *(const bf16x8*)(tB + (m * 16 + lr) * 120 + 96 + kq * 8) : z;
        }
        acc = MFMA(a, b[c], acc);
      }
#pragma unroll
      for (int rr = 0; rr < 4; rr++)
        tA[(m * 16 + kq * 4 + rr) * 120 + nb + lr] = (bf16_t)fmaxf(acc[rr], 0.f);
    }
  }
  __syncthreads();  // B8

  // ---- S8: h2 = h2b @ Wu3^T + b_u3 -> out[:,160:224]. wave: nb=(w&3)*16, rows half w>>2 ----
  {
    int nb = (w & 3) * 16;
    int rh = w >> 2;
    float bv = b_u3[nb + lr];
    const bf16_t* Bp = wb + OFF_WU3 + (nb + lr) * 128 + kq * 8;
    bf16x8 b[4];
#pragma unroll
    for (int c = 0; c < 4; c++) b[c] = *(const bf16x8*)(Bp + c * 32);
#pragma unroll
    for (int mm = 0; mm < 4; mm++) {
      int m = rh * 4 + mm;
      f32x4 acc = {bv, bv, bv, bv};
#pragma unroll
      for (int c = 0; c < 4; c++) {
        bf16x8 a;
        if (c < 3) {
          a = *(const bf16x8*)(tA + (m * 16 + lr) * 120 + c * 32 + kq * 8);
        } else {
          bf16x8 z = {};
          a = (kq < 2) ? *(const bf16x8*)(tA + (m * 16 + lr) * 120 + 96 + kq * 8) : z;
        }
        acc = MFMA(a, b[c], acc);
      }
#pragma unroll
      for (int rr = 0; rr < 4; rr++) {
        size_t row = row0 + m * 16 + kq * 4 + rr;
        out[row * OUTC + 160 + nb + lr] = acc[rr];
      }
    }
  }

  // ---- S9 (same window): mu/var = h2b @ E^T + bmv. wave: t=w&1, m-tiles {w>>1, +4} ----
  {
    int t = w & 1;
    const bf16_t* Bp = wb + OFF_WMV2 + (t * 16 + lr) * 112 + kq * 8;
    bf16x8 b[4];
#pragma unroll
    for (int c = 0; c < 3; c++) b[c] = *(const bf16x8*)(Bp + c * 32);
    {
      bf16x8 z = {};
      b[3] = (kq < 2) ? *(const bf16x8*)(Bp + 96) : z;
    }
    float bv = bmv[t * 16 + lr];
    float mx = maxlv[lr], mn = minlv[lr];
#pragma unroll
    for (int mi = 0; mi < 2; mi++) {
      int m = (w >> 1) + mi * 4;
      f32x4 acc = {bv, bv, bv, bv};
#pragma unroll
      for (int c = 0; c < 4; c++) {
        bf16x8 a;
        if (c < 3) {
          a = *(const bf16x8*)(tA + (m * 16 + lr) * 120 + c * 32 + kq * 8);
        } else {
          bf16x8 z = {};
          a = (kq < 2) ? *(const bf16x8*)(tA + (m * 16 + lr) * 120 + 96 + kq * 8) : z;
        }
        acc = MFMA(a, b[c], acc);
      }
      if (t == 0) {
#pragma unroll
        for (int rr = 0; rr < 4; rr++) {
          size_t row = row0 + m * 16 + kq * 4 + rr;
          out[row * OUTC + lr] = acc[rr];
        }
      } else {
#pragma unroll
        for (int rr = 0; rr < 4; rr++) {
          size_t row = row0 + m * 16 + kq * 4 + rr;
          float lv = acc[rr];
          lv = mx - fsoftplus(mx - lv);
          lv = mn + fsoftplus(lv - mn);
          out[row * OUTC + 16 + lr] = __expf(lv);
        }
      }
    }
  }
}

extern "C" void kernel_launch(void* const* d_in, const int* in_sizes, int n_in,
                              void* d_out, int out_size, void* d_ws, size_t ws_size,
                              hipStream_t stream) {
  const float* obs   = (const float*)d_in[0];
  const float* msgs  = (const float*)d_in[1];
  const float* h_l   = (const float*)d_in[2];
  const float* c_l   = (const float*)d_in[3];
  const float* W_in  = (const float*)d_in[4];
  const float* b_in  = (const float*)d_in[5];
  const float* mW1   = (const float*)d_in[6];
  const float* mb1   = (const float*)d_in[7];
  const float* mW2   = (const float*)d_in[8];
  const float* mb2   = (const float*)d_in[9];
  const float* W_ih  = (const float*)d_in[10];
  const float* W_hh  = (const float*)d_in[11];
  const float* b_ih  = (const float*)d_in[12];
  const float* b_hh  = (const float*)d_in[13];
  const float* W_u1  = (const float*)d_in[14];
  const float* b_u1  = (const float*)d_in[15];
  const float* W_u2  = (const float*)d_in[16];
  const float* b_u2  = (const float*)d_in[17];
  const float* W_u3  = (const float*)d_in[18];
  const float* b_u3  = (const float*)d_in[19];
  const float* W_mu  = (const float*)d_in[20];
  const float* b_mu  = (const float*)d_in[21];
  const float* W_var = (const float*)d_in[22];
  const float* b_var = (const float*)d_in[23];
  const float* maxlv = (const float*)d_in[24];
  const float* minlv = (const float*)d_in[25];

  bf16_t* wb = (bf16_t*)d_ws;
  float* bg  = (float*)((char*)d_ws + (size_t)BF16_TOTAL * 2);
  float* bmv = bg + 256;

  prep_kernel<<<64, 256, 0, stream>>>(W_in, mW1, mW2, W_ih, W_hh, b_ih, b_hh,
                                      W_u1, W_u2, W_u3, b_u3, W_mu, W_var, b_mu, b_var,
                                      wb, bg, bmv);
  fused_kernel<<<B_TOTAL / ROWS, 512, 0, stream>>>(
      obs, msgs, h_l, c_l, b_in, mb1, mb2, b_u1, b_u2, b_u3,
      maxlv, minlv, wb, bg, bmv, (float*)d_out);
}

// Round 14
// 347.615 us; speedup vs baseline: 1.0174x; 1.0174x over previous
//
#include <hip/hip_runtime.h>

typedef __bf16 bf16_t;
typedef __bf16 bf16x8 __attribute__((ext_vector_type(8)));
typedef float f32x4 __attribute__((ext_vector_type(4)));

#define B_TOTAL 262144
#define OUTC 324
#define ROWS 64

// d_ws layout (bf16 element offsets)
#define OFF_WIN   0        // [64][32]
#define OFF_WG    2048     // [256][256] gate-major: n = g*64 + j; K = [x64|msgs128|h64]
#define OFF_WM1   67584    // [4][112][64]
#define OFF_WM2   96256    // [4][32][128]
#define OFF_WU1   112640   // [112][64]
#define OFF_WU2   119808   // [112][128]
#define OFF_WU3   134144   // [64][128]
#define OFF_WMV2  142336   // [32][112] fused (Wmu;Wvar)·Wu3
#define BF16_TOTAL 145920
// f32: bg[256] at byte BF16_TOTAL*2; bmv[32] after

__global__ void prep_kernel(const float* W_in, const float* msg_W1, const float* msg_W2,
                            const float* W_ih, const float* W_hh, const float* b_ih, const float* b_hh,
                            const float* W_u1, const float* W_u2, const float* W_u3, const float* b_u3f,
                            const float* W_mu, const float* W_var, const float* b_mu, const float* b_var,
                            bf16_t* wb, float* bg, float* bmv) {
  int tid = blockIdx.x * blockDim.x + threadIdx.x;
  int nth = gridDim.x * blockDim.x;
  for (int i = tid; i < 2048; i += nth) wb[OFF_WIN + i] = (bf16_t)W_in[i];
  for (int i = tid; i < 65536; i += nth) {
    int n = i >> 8, k = i & 255;
    int g = n >> 6, j = n & 63;
    float v = 0.f;
    if (j < 50) {
      int r = g * 50 + j;
      if (k < 192) v = W_ih[r * 192 + k];
      else if (k < 242) v = W_hh[r * 50 + (k - 192)];
    }
    wb[OFF_WG + i] = (bf16_t)v;
  }
  for (int i = tid; i < 256; i += nth) {
    int g = i >> 6, j = i & 63;
    bg[i] = (j < 50) ? (b_ih[g * 50 + j] + b_hh[g * 50 + j]) : 0.f;
  }
  for (int i = tid; i < 4 * 112 * 64; i += nth) {
    int p = i / (112 * 64); int rem = i % (112 * 64); int n = rem >> 6, k = rem & 63;
    wb[OFF_WM1 + i] = (bf16_t)((n < 100) ? msg_W1[(p * 100 + n) * 64 + k] : 0.f);
  }
  for (int i = tid; i < 4 * 32 * 128; i += nth) {
    int p = i / (32 * 128); int rem = i % (32 * 128); int n = rem >> 7, k = rem & 127;
    wb[OFF_WM2 + i] = (bf16_t)((k < 100) ? msg_W2[(p * 32 + n) * 100 + k] : 0.f);
  }
  for (int i = tid; i < 112 * 64; i += nth) {
    int n = i >> 6, k = i & 63;
    wb[OFF_WU1 + i] = (bf16_t)((n < 100 && k < 50) ? W_u1[n * 50 + k] : 0.f);
  }
  for (int i = tid; i < 112 * 128; i += nth) {
    int n = i >> 7, k = i & 127;
    wb[OFF_WU2 + i] = (bf16_t)((n < 100 && k < 100) ? W_u2[n * 100 + k] : 0.f);
  }
  for (int i = tid; i < 64 * 128; i += nth) {
    int n = i >> 7, k = i & 127;
    wb[OFF_WU3 + i] = (bf16_t)((k < 100) ? W_u3[n * 100 + k] : 0.f);
  }
  for (int i = tid; i < 32 * 112; i += nth) {
    int o = i / 112, h = i % 112;
    float v = 0.f;
    if (h < 100) {
      const float* wrow = (o < 16) ? (W_mu + o * 64) : (W_var + (o - 16) * 64);
      for (int s = 0; s < 64; s++) v += wrow[s] * W_u3[s * 100 + h];
    }
    wb[OFF_WMV2 + i] = (bf16_t)v;
  }
  for (int i = tid; i < 32; i += nth) {
    int o = i;
    const float* wrow = (o < 16) ? (W_mu + o * 64) : (W_var + (o - 16) * 64);
    float v = (o < 16) ? b_mu[o] : b_var[o - 16];
    for (int s = 0; s < 64; s++) v += wrow[s] * b_u3f[s];
    bmv[o] = v;
  }
}

#define MFMA(a, b, c) __builtin_amdgcn_mfma_f32_16x16x32_bf16((a), (b), (c), 0, 0, 0)

__device__ __forceinline__ float frcp(float x) { return __builtin_amdgcn_rcpf(x); }
__device__ __forceinline__ float fsigmoid(float x) { return frcp(1.f + __expf(-x)); }
__device__ __forceinline__ float ftanh_f(float x) { return 1.f - 2.f * frcp(1.f + __expf(2.f * x)); }
__device__ __forceinline__ float fsoftplus(float x) { return (x > 15.f) ? x : __logf(1.f + __expf(x)); }

// LDS-only barrier: drains this wave's DS ops (lgkmcnt) then s_barrier.
// Unlike __syncthreads, does NOT wait vmcnt(0) — in-flight global STORES (which
// nothing ever reads) keep draining in the background instead of stalling every
// window. Load-use waits are still auto-inserted by the compiler. sched_barrier
// fences per guide rule 18 (compiler may otherwise migrate ops across inline asm).
__device__ __forceinline__ void barrier_lds() {
  __builtin_amdgcn_sched_barrier(0);
  asm volatile("s_waitcnt lgkmcnt(0)" ::: "memory");
  __builtin_amdgcn_s_barrier();
  __builtin_amdgcn_sched_barrier(0);
}

__device__ __forceinline__ bf16x8 cvt8(const float* __restrict__ p) {
  float4 v0 = *(const float4*)p;
  float4 v1 = *(const float4*)(p + 4);
  bf16x8 r;
  r[0] = (bf16_t)v0.x; r[1] = (bf16_t)v0.y; r[2] = (bf16_t)v0.z; r[3] = (bf16_t)v0.w;
  r[4] = (bf16_t)v1.x; r[5] = (bf16_t)v1.y; r[6] = (bf16_t)v1.z; r[7] = (bf16_t)v1.w;
  return r;
}

// S2: m1(p) = relu(x @ W1p^T + b1p) -> dst[:,0:112]  (cross-wave n-split, m=4)
__device__ __forceinline__ void stage2(int p, const bf16x8 ax[4][2], bf16_t* dst,
                                       const bf16_t* __restrict__ wb,
                                       const float* __restrict__ msg_b1,
                                       int w, int lr, int kq) {
  for (int nt = w; nt < 7; nt += 4) {
    int nb = nt * 16;
    float bv = (nb + lr < 100) ? msg_b1[p * 100 + nb + lr] : 0.f;
    const bf16_t* Bp = wb + OFF_WM1 + p * 112 * 64 + (nb + lr) * 64 + kq * 8;
    bf16x8 b0 = *(const bf16x8*)Bp;
    bf16x8 b1 = *(const bf16x8*)(Bp + 32);
#pragma unroll
    for (int m = 0; m < 4; m++) {
      f32x4 acc = {bv, bv, bv, bv};
      acc = MFMA(ax[m][0], b0, acc);
      acc = MFMA(ax[m][1], b1, acc);
#pragma unroll
      for (int rr = 0; rr < 4; rr++)
        dst[(m * 16 + kq * 4 + rr) * 120 + nb + lr] = (bf16_t)fmaxf(acc[rr], 0.f);
    }
  }
}

// S3: msgs(p) = m1 @ W2p^T + b2p -> out[:, 32+32p : 64+32p]
__device__ __forceinline__ void stage3(int p, const bf16_t* src,
                                       const bf16_t* __restrict__ wb,
                                       const float* __restrict__ msg_b2,
                                       float* __restrict__ out,
                                       int row0, int w, int lr, int kq) {
  int nb = (w & 1) * 16;
  float bv = msg_b2[p * 32 + nb + lr];
  const bf16_t* Bp = wb + OFF_WM2 + p * 32 * 128 + (nb + lr) * 128 + kq * 8;
  bf16x8 b[4];
#pragma unroll
  for (int c = 0; c < 4; c++) b[c] = *(const bf16x8*)(Bp + c * 32);
#pragma unroll
  for (int mi = 0; mi < 2; mi++) {
    int m = (w >> 1) + mi * 2;
    f32x4 acc = {bv, bv, bv, bv};
#pragma unroll
    for (int c = 0; c < 4; c++) {
      bf16x8 a;
      if (c < 3) {
        a = *(const bf16x8*)(src + (m * 16 + lr) * 120 + c * 32 + kq * 8);
      } else {
        bf16x8 z = {};
        a = (kq < 2) ? *(const bf16x8*)(src + (m * 16 + lr) * 120 + 96 + kq * 8) : z;
      }
      acc = MFMA(a, b[c], acc);
    }
#pragma unroll
    for (int rr = 0; rr < 4; rr++) {
      size_t row = row0 + m * 16 + kq * 4 + rr;
      out[row * OUTC + 32 + p * 32 + nb + lr] = acc[rr];
    }
  }
}

// LDS: xh[64][72] (x -> stays live through S4), tA[64][120], tB[64][120] = 39936 B
__global__ __launch_bounds__(256, 2) void fused_kernel(
    const float* __restrict__ obs, const float* __restrict__ msg_in,
    const float* __restrict__ h_lstm, const float* __restrict__ c_lstm,
    const float* __restrict__ b_in, const float* __restrict__ msg_b1,
    const float* __restrict__ msg_b2, const float* __restrict__ b_u1,
    const float* __restrict__ b_u2, const float* __restrict__ b_u3,
    const float* __restrict__ maxlv, const float* __restrict__ minlv,
    const bf16_t* __restrict__ wb, const float* __restrict__ bg,
    const float* __restrict__ bmv, float* __restrict__ out) {
  __shared__ __align__(16) bf16_t xh[ROWS * 72];
  __shared__ __align__(16) bf16_t tA[ROWS * 120];
  __shared__ __align__(16) bf16_t tB[ROWS * 120];

  const int tid = threadIdx.x;
  const int row0 = blockIdx.x * ROWS;
  const int lane = tid & 63;
  const int w = tid >> 6;
  const int lr = lane & 15;
  const int kq = lane >> 4;

  // ---- S1: x = relu(obs @ Win^T + b_in) -> xh[:,0:64] ----
  {
    int nb = w * 16;
    float bv = b_in[nb + lr];
    bf16x8 b0 = *(const bf16x8*)(wb + OFF_WIN + (nb + lr) * 32 + kq * 8);
#pragma unroll
    for (int m = 0; m < 4; m++) {
      bf16x8 a0 = cvt8(obs + (size_t)(row0 + m * 16 + lr) * 32 + kq * 8);
      f32x4 acc = {bv, bv, bv, bv};
      acc = MFMA(a0, b0, acc);
#pragma unroll
      for (int rr = 0; rr < 4; rr++)
        xh[(m * 16 + kq * 4 + rr) * 72 + nb + lr] = (bf16_t)fmaxf(acc[rr], 0.f);
    }
  }
  barrier_lds();  // B1

  // hoist x A-fragments (S2 only; S4 re-reads x from LDS)
  bf16x8 ax[4][2];
#pragma unroll
  for (int m = 0; m < 4; m++)
#pragma unroll
    for (int k = 0; k < 2; k++)
      ax[m][k] = *(const bf16x8*)(xh + (m * 16 + lr) * 72 + k * 32 + kq * 8);

  stage2(0, ax, tA, wb, msg_b1, w, lr, kq);
  barrier_lds();  // B2

  stage3(0, tA, wb, msg_b2, out, row0, w, lr, kq);
  stage2(1, ax, tB, wb, msg_b1, w, lr, kq);
  barrier_lds();  // B3
  stage3(1, tB, wb, msg_b2, out, row0, w, lr, kq);
  stage2(2, ax, tA, wb, msg_b1, w, lr, kq);
  barrier_lds();  // B4
  stage3(2, tA, wb, msg_b2, out, row0, w, lr, kq);
  stage2(3, ax, tB, wb, msg_b1, w, lr, kq);
  barrier_lds();  // B5

  // ---- window: S3(3) || S4 gates — wave w owns j = 16w+lr for ALL 64 rows ----
  // Gate weights read exactly ONCE per block: 32 B-insts/wave.
  {
    const int j = w * 16 + lr;
    // prefetch c_lstm for the epilogue (16 f32)
    float c_pre[4][4];
#pragma unroll
    for (int ms = 0; ms < 4; ms++)
#pragma unroll
      for (int rr = 0; rr < 4; rr++) {
        size_t row = row0 + ms * 16 + kq * 4 + rr;
        c_pre[ms][rr] = (j < 50) ? c_lstm[row * 50 + j] : 0.f;
      }

    stage3(3, tB, wb, msg_b2, out, row0, w, lr, kq);

    f32x4 acc[4][4];  // [gate][ms]
#pragma unroll
    for (int g = 0; g < 4; g++) {
      float bb = bg[g * 64 + j];
      f32x4 bi = {bb, bb, bb, bb};
#pragma unroll
      for (int ms = 0; ms < 4; ms++) acc[g][ms] = bi;
    }
#pragma unroll
    for (int c = 0; c < 8; c++) {
      bf16x8 a[4];
#pragma unroll
      for (int ms = 0; ms < 4; ms++) {
        int lrow = ms * 16 + lr;
        if (c < 2) {
          a[ms] = *(const bf16x8*)(xh + lrow * 72 + c * 32 + kq * 8);
        } else if (c < 6) {
          a[ms] = cvt8(msg_in + ((size_t)(c - 2) * B_TOTAL + row0 + lrow) * 32 + kq * 8);
        } else if (c == 6) {
          a[ms] = cvt8(h_lstm + (size_t)(row0 + lrow) * 50 + kq * 8);
        } else {
          const float* hp = h_lstm + (size_t)(row0 + lrow) * 50;
          if (kq < 2) {
            a[ms] = cvt8(hp + 32 + kq * 8);
          } else if (kq == 2) {
            bf16x8 r = {};
            float2 v = *(const float2*)(hp + 48);
            r[0] = (bf16_t)v.x; r[1] = (bf16_t)v.y;
            a[ms] = r;
          } else {
            bf16x8 r = {};
            a[ms] = r;
          }
        }
      }
      bf16x8 bfr[4];
#pragma unroll
      for (int g = 0; g < 4; g++)
        bfr[g] = *(const bf16x8*)(wb + OFF_WG + (size_t)(g * 64 + j) * 256 + c * 32 + kq * 8);
#pragma unroll
      for (int g = 0; g < 4; g++)
#pragma unroll
        for (int ms = 0; ms < 4; ms++)
          acc[g][ms] = MFMA(a[ms], bfr[g], acc[g][ms]);
    }
    // LSTM epilogue; hn -> tA
#pragma unroll
    for (int ms = 0; ms < 4; ms++) {
#pragma unroll
      for (int rr = 0; rr < 4; rr++) {
        int lrow = ms * 16 + kq * 4 + rr;
        size_t row = row0 + lrow;
        float si = fsigmoid(acc[0][ms][rr]);
        float sf = fsigmoid(acc[1][ms][rr]);
        float gv = ftanh_f(acc[2][ms][rr]);
        float so = fsigmoid(acc[3][ms][rr]);
        float cn = sf * c_pre[ms][rr] + si * gv;
        float hv = so * ftanh_f(cn);
        if (j < 50) {
          out[row * OUTC + 274 + j] = cn;
          out[row * OUTC + 224 + j] = hv;
        }
        tA[lrow * 120 + j] = (bf16_t)((j < 50) ? hv : 0.f);
      }
    }
  }
  barrier_lds();  // B6

  // ---- S6: h2a = relu(hn @ Wu1^T + b_u1) -> tB[:,0:112] ----
  for (int nt = w; nt < 7; nt += 4) {
    int nb = nt * 16;
    float bv = (nb + lr < 100) ? b_u1[nb + lr] : 0.f;
    const bf16_t* Bp = wb + OFF_WU1 + (nb + lr) * 64 + kq * 8;
    bf16x8 b0 = *(const bf16x8*)Bp;
    bf16x8 b1 = *(const bf16x8*)(Bp + 32);
#pragma unroll
    for (int m = 0; m < 4; m++) {
      bf16x8 a0 = *(const bf16x8*)(tA + (m * 16 + lr) * 120 + kq * 8);
      bf16x8 a1 = *(const bf16x8*)(tA + (m * 16 + lr) * 120 + kq * 8 + 32);
      f32x4 acc = {bv, bv, bv, bv};
      acc = MFMA(a0, b0, acc);
      acc = MFMA(a1, b1, acc);
#pragma unroll
      for (int rr = 0; rr < 4; rr++)
        tB[(m * 16 + kq * 4 + rr) * 120 + nb + lr] = (bf16_t)fmaxf(acc[rr], 0.f);
    }
  }
  barrier_lds();  // B7

  // ---- S7: h2b = relu(h2a @ Wu2^T + b_u2) -> tA[:,0:112] ----
  for (int nt = w; nt < 7; nt += 4) {
    int nb = nt * 16;
    float bv = (nb + lr < 100) ? b_u2[nb + lr] : 0.f;
    const bf16_t* Bp = wb + OFF_WU2 + (nb + lr) * 128 + kq * 8;
    bf16x8 b[4];
#pragma unroll
    for (int c = 0; c < 4; c++) b[c] = *(const bf16x8*)(Bp + c * 32);
#pragma unroll
    for (int m = 0; m < 4; m++) {
      f32x4 acc = {bv, bv, bv, bv};
#pragma unroll
      for (int c = 0; c < 4; c++) {
        bf16x8 a;
        if (c < 3) {
          a = *(const bf16x8*)(tB + (m * 16 + lr) * 120 + c * 32 + kq * 8);
        } else {
          bf16x8 z = {};
          a = (kq < 2) ? *(const bf16x8*)(tB + (m * 16 + lr) * 120 + 96 + kq * 8) : z;
        }
        acc = MFMA(a, b[c], acc);
      }
#pragma unroll
      for (int rr = 0; rr < 4; rr++)
        tA[(m * 16 + kq * 4 + rr) * 120 + nb + lr] = (bf16_t)fmaxf(acc[rr], 0.f);
    }
  }
  barrier_lds();  // B8

  // ---- S8: h2 = h2b @ Wu3^T + b_u3 -> out[:,160:224] ----
  {
    int nb = w * 16;
    float bv = b_u3[nb + lr];
    const bf16_t* Bp = wb + OFF_WU3 + (nb + lr) * 128 + kq * 8;
    bf16x8 b[4];
#pragma unroll
    for (int c = 0; c < 4; c++) b[c] = *(const bf16x8*)(Bp + c * 32);
#pragma unroll
    for (int m = 0; m < 4; m++) {
      f32x4 acc = {bv, bv, bv, bv};
#pragma unroll
      for (int c = 0; c < 4; c++) {
        bf16x8 a;
        if (c < 3) {
          a = *(const bf16x8*)(tA + (m * 16 + lr) * 120 + c * 32 + kq * 8);
        } else {
          bf16x8 z = {};
          a = (kq < 2) ? *(const bf16x8*)(tA + (m * 16 + lr) * 120 + 96 + kq * 8) : z;
        }
        acc = MFMA(a, b[c], acc);
      }
#pragma unroll
      for (int rr = 0; rr < 4; rr++) {
        size_t row = row0 + m * 16 + kq * 4 + rr;
        out[row * OUTC + 160 + nb + lr] = acc[rr];
      }
    }
  }

  // ---- S9 (same window; read-only on tA): mu/var = h2b @ E^T + bmv ----
  {
    int t = w & 1;
    const bf16_t* Bp = wb + OFF_WMV2 + (t * 16 + lr) * 112 + kq * 8;
    bf16x8 b[4];
#pragma unroll
    for (int c = 0; c < 3; c++) b[c] = *(const bf16x8*)(Bp + c * 32);
    {
      bf16x8 z = {};
      b[3] = (kq < 2) ? *(const bf16x8*)(Bp + 96) : z;
    }
    float bv = bmv[t * 16 + lr];
    float mx = maxlv[lr], mn = minlv[lr];
#pragma unroll
    for (int mi = 0; mi < 2; mi++) {
      int m = (w >> 1) + mi * 2;
      f32x4 acc = {bv, bv, bv, bv};
#pragma unroll
      for (int c = 0; c < 4; c++) {
        bf16x8 a;
        if (c < 3) {
          a = *(const bf16x8*)(tA + (m * 16 + lr) * 120 + c * 32 + kq * 8);
        } else {
          bf16x8 z = {};
          a = (kq < 2) ? *(const bf16x8*)(tA + (m * 16 + lr) * 120 + 96 + kq * 8) : z;
        }
        acc = MFMA(a, b[c], acc);
      }
      if (t == 0) {
#pragma unroll
        for (int rr = 0; rr < 4; rr++) {
          size_t row = row0 + m * 16 + kq * 4 + rr;
          out[row * OUTC + lr] = acc[rr];
        }
      } else {
#pragma unroll
        for (int rr = 0; rr < 4; rr++) {
          size_t row = row0 + m * 16 + kq * 4 + rr;
          float lv = acc[rr];
          lv = mx - fsoftplus(mx - lv);
          lv = mn + fsoftplus(lv - mn);
          out[row * OUTC + 16 + lr] = __expf(lv);
        }
      }
    }
  }
}

extern "C" void kernel_launch(void* const* d_in, const int* in_sizes, int n_in,
                              void* d_out, int out_size, void* d_ws, size_t ws_size,
                              hipStream_t stream) {
  const float* obs   = (const float*)d_in[0];
  const float* msgs  = (const float*)d_in[1];
  const float* h_l   = (const float*)d_in[2];
  const float* c_l   = (const float*)d_in[3];
  const float* W_in  = (const float*)d_in[4];
  const float* b_in  = (const float*)d_in[5];
  const float* mW1   = (const float*)d_in[6];
  const float* mb1   = (const float*)d_in[7];
  const float* mW2   = (const float*)d_in[8];
  const float* mb2   = (const float*)d_in[9];
  const float* W_ih  = (const float*)d_in[10];
  const float* W_hh  = (const float*)d_in[11];
  const float* b_ih  = (const float*)d_in[12];
  const float* b_hh  = (const float*)d_in[13];
  const float* W_u1  = (const float*)d_in[14];
  const float* b_u1  = (const float*)d_in[15];
  const float* W_u2  = (const float*)d_in[16];
  const float* b_u2  = (const float*)d_in[17];
  const float* W_u3  = (const float*)d_in[18];
  const float* b_u3  = (const float*)d_in[19];
  const float* W_mu  = (const float*)d_in[20];
  const float* b_mu  = (const float*)d_in[21];
  const float* W_var = (const float*)d_in[22];
  const float* b_var = (const float*)d_in[23];
  const float* maxlv = (const float*)d_in[24];
  const float* minlv = (const float*)d_in[25];

  bf16_t* wb = (bf16_t*)d_ws;
  float* bg  = (float*)((char*)d_ws + (size_t)BF16_TOTAL * 2);
  float* bmv = bg + 256;

  prep_kernel<<<64, 256, 0, stream>>>(W_in, mW1, mW2, W_ih, W_hh, b_ih, b_hh,
                                      W_u1, W_u2, W_u3, b_u3, W_mu, W_var, b_mu, b_var,
                                      wb, bg, bmv);
  fused_kernel<<<B_TOTAL / ROWS, 256, 0, stream>>>(
      obs, msgs, h_l, c_l, b_in, mb1, mb2, b_u1, b_u2, b_u3,
      maxlv, minlv, wb, bg, bmv, (float*)d_out);
}